// Round 1
// baseline (1184.536 us; speedup 1.0000x reference)
//
#include <hip/hip_runtime.h>
#include <hip/hip_bf16.h>
#include <math.h>

typedef short s8v __attribute__((ext_vector_type(8)));
typedef short s4v __attribute__((ext_vector_type(4)));
typedef __bf16 bf8v __attribute__((ext_vector_type(8)));
typedef float f4v __attribute__((ext_vector_type(4)));

static __device__ __forceinline__ float bf2f(ushort u) {
  return __builtin_bit_cast(float, (unsigned int)u << 16);
}
static __device__ __forceinline__ ushort f2bf(float f) {
  unsigned int u = __builtin_bit_cast(unsigned int, f);
  u += 0x7FFFu + ((u >> 16) & 1u);
  return (ushort)(u >> 16);
}
static __device__ __forceinline__ float gelu_f(float v) {
  return 0.5f * v * (1.0f + erff(v * 0.70710678118654752f));
}
static __device__ __forceinline__ float wave_max_f(float v) {
  #pragma unroll
  for (int o = 32; o >= 1; o >>= 1) v = fmaxf(v, __shfl_xor(v, o));
  return v;
}
static __device__ __forceinline__ float wave_sum_f(float v) {
  #pragma unroll
  for (int o = 32; o >= 1; o >>= 1) v += __shfl_xor(v, o);
  return v;
}

// ---------------- weight fp32 -> bf16 convert ----------------
__global__ void cvt_f32_bf16(const float* __restrict__ in, ushort* __restrict__ out, int n) {
  int i = (blockIdx.x * 256 + threadIdx.x) * 4;
  if (i >= n) return;
  float4 v = *(const float4*)(in + i);
  s4v o;
  o[0] = (short)f2bf(v.x); o[1] = (short)f2bf(v.y);
  o[2] = (short)f2bf(v.z); o[3] = (short)f2bf(v.w);
  *(s4v*)(out + i) = o;
}

// ---------------- LayerNorm over D=512, one wave per row ----------------
__global__ __launch_bounds__(256) void ln_rows(
    const float* __restrict__ x, const float* __restrict__ gam,
    const float* __restrict__ bet, const float* __restrict__ mask,
    ushort* __restrict__ out)
{
  const int tid = threadIdx.x, lane = tid & 63, wv = tid >> 6;
  const long row = (long)blockIdx.x * 4 + wv;
  const float* xp = x + row * 512 + lane * 8;
  float4 a = *(const float4*)xp;
  float4 b = *(const float4*)(xp + 4);
  float s = a.x + a.y + a.z + a.w + b.x + b.y + b.z + b.w;
  float q = a.x*a.x + a.y*a.y + a.z*a.z + a.w*a.w
          + b.x*b.x + b.y*b.y + b.z*b.z + b.w*b.w;
  s = wave_sum_f(s); q = wave_sum_f(q);
  float m = s * (1.f / 512.f);
  float var = q * (1.f / 512.f) - m * m;
  float r = rsqrtf(var + 1e-5f);
  float mk = mask ? mask[row] : 1.f;
  const float* gp = gam + lane * 8;
  const float* bp = bet + lane * 8;
  float4 g0 = *(const float4*)gp, g1 = *(const float4*)(gp + 4);
  float4 c0 = *(const float4*)bp, c1 = *(const float4*)(bp + 4);
  s8v o;
  o[0] = (short)f2bf(((a.x - m) * r * g0.x + c0.x) * mk);
  o[1] = (short)f2bf(((a.y - m) * r * g0.y + c0.y) * mk);
  o[2] = (short)f2bf(((a.z - m) * r * g0.z + c0.z) * mk);
  o[3] = (short)f2bf(((a.w - m) * r * g0.w + c0.w) * mk);
  o[4] = (short)f2bf(((b.x - m) * r * g1.x + c1.x) * mk);
  o[5] = (short)f2bf(((b.y - m) * r * g1.y + c1.y) * mk);
  o[6] = (short)f2bf(((b.z - m) * r * g1.z + c1.z) * mk);
  o[7] = (short)f2bf(((b.w - m) * r * g1.w + c1.w) * mk);
  *(s8v*)(out + row * 512 + lane * 8) = o;
}

// ---------------- bf16 GEMM: C[M,N] = A[M,K] @ W[N,K]^T, fused epilogues ---
// EPI 0: out bf16 = v + bias
// EPI 1: out f32  = v + bias + resid
// EPI 2: out bf16 = gelu(v + bias)
// EPI 3: out f32  = (resid + gelu(v + bias)) * mask[row]
#define BMT 128
#define BNT 128
#define BKT 64

template<int EPI>
__global__ __launch_bounds__(256, 2) void gemm_bt(
    const ushort* __restrict__ A, const ushort* __restrict__ W,
    const float* __restrict__ bias, const float* __restrict__ resid,
    const float* __restrict__ mask, void* __restrict__ Out,
    int M, int N, int K)
{
  __shared__ __align__(16) ushort lsA[BMT * BKT];
  __shared__ __align__(16) ushort lsB[BNT * BKT];
  const int tid = threadIdx.x;
  const int lane = tid & 63;
  const int wid = tid >> 6;
  const int wr = wid >> 1, wc = wid & 1;
  const long bm = (long)blockIdx.y * BMT;
  const int bn = blockIdx.x * BNT;

  f4v acc[4][4] = {};

  const int r0 = tid >> 3;        // 0..31
  const int c8 = (tid & 7) * 8;   // 0,8,...,56

  for (int k0 = 0; k0 < K; k0 += BKT) {
    __syncthreads();
    #pragma unroll
    for (int p = 0; p < 4; ++p) {
      int row = r0 + p * 32;
      int sc = c8 ^ ((row & 7) << 3);
      s8v va = *(const s8v*)(A + (bm + row) * K + k0 + c8);
      *(s8v*)(lsA + row * BKT + sc) = va;
      s8v vb = *(const s8v*)(W + (long)(bn + row) * K + k0 + c8);
      *(s8v*)(lsB + row * BKT + sc) = vb;
    }
    __syncthreads();
    #pragma unroll
    for (int kk = 0; kk < 2; ++kk) {
      const int kb = kk * 32 + (lane >> 4) * 8;
      bf8v af[4], bf[4];
      #pragma unroll
      for (int m = 0; m < 4; ++m) {
        int row = wr * 64 + m * 16 + (lane & 15);
        af[m] = *(const bf8v*)(lsA + row * BKT + (kb ^ ((row & 7) << 3)));
      }
      #pragma unroll
      for (int n = 0; n < 4; ++n) {
        int row = wc * 64 + n * 16 + (lane & 15);
        bf[n] = *(const bf8v*)(lsB + row * BKT + (kb ^ ((row & 7) << 3)));
      }
      #pragma unroll
      for (int m = 0; m < 4; ++m)
        #pragma unroll
        for (int n = 0; n < 4; ++n)
          acc[m][n] = __builtin_amdgcn_mfma_f32_16x16x32_bf16(af[m], bf[n], acc[m][n], 0, 0, 0);
    }
  }

  const int colbase = bn + wc * 64 + (lane & 15);
  const long rowbase = bm + wr * 64 + ((lane >> 4) * 4);
  #pragma unroll
  for (int m = 0; m < 4; ++m) {
    #pragma unroll
    for (int j = 0; j < 4; ++j) {
      const long row = rowbase + m * 16 + j;
      #pragma unroll
      for (int n = 0; n < 4; ++n) {
        const int col = colbase + n * 16;
        float v = acc[m][n][j] + bias[col];
        const long idx = row * N + col;
        if constexpr (EPI == 0) {
          ((ushort*)Out)[idx] = f2bf(v);
        } else if constexpr (EPI == 1) {
          ((float*)Out)[idx] = v + resid[idx];
        } else if constexpr (EPI == 2) {
          ((ushort*)Out)[idx] = f2bf(gelu_f(v));
        } else {
          ((float*)Out)[idx] = (resid[idx] + gelu_f(v)) * mask[row];
        }
      }
    }
  }
}

// ---------------- stage 1 pooling: softmax over N of Q·q_alpha, weighted Q sum
__global__ __launch_bounds__(1024) void pool_stage1(
    const ushort* __restrict__ Q, const float* __restrict__ qa,
    const float* __restrict__ mask, float* __restrict__ gq)
{
  __shared__ float sl[8192];
  __shared__ float red[16];
  __shared__ float sca[64];
  __shared__ float bcast;
  const int bh = blockIdx.x;
  const int b = bh >> 3, h = bh & 7;
  const int tid = threadIdx.x, lane = tid & 63, wv = tid >> 6;
  if (tid < 64) sca[tid] = qa[h * 64 + tid];
  __syncthreads();
  const float scale = 0.125f;
  float lmax = -INFINITY;
  for (int n = tid; n < 8192; n += 1024) {
    const ushort* qp = Q + ((long)(b * 8192 + n) * 512 + h * 64);
    float dot = 0.f;
    #pragma unroll
    for (int c = 0; c < 8; ++c) {
      s8v v = *(const s8v*)(qp + c * 8);
      #pragma unroll
      for (int j = 0; j < 8; ++j) dot += bf2f((ushort)v[j]) * sca[c * 8 + j];
    }
    float lg = dot * scale;
    if (mask[b * 8192 + n] == 0.f) lg = -INFINITY;
    sl[n] = lg;
    lmax = fmaxf(lmax, lg);
  }
  lmax = wave_max_f(lmax);
  if (lane == 0) red[wv] = lmax;
  __syncthreads();
  if (tid < 64) {
    float v = (lane < 16) ? red[lane] : -INFINITY;
    v = wave_max_f(v);
    if (lane == 0) bcast = v;
  }
  __syncthreads();
  const float gmax = bcast;
  float lsum = 0.f;
  for (int n = tid; n < 8192; n += 1024) {
    float e = __expf(sl[n] - gmax);
    sl[n] = e;
    lsum += e;
  }
  lsum = wave_sum_f(lsum);
  __syncthreads();
  if (lane == 0) red[wv] = lsum;
  __syncthreads();
  if (tid < 64) {
    float v = (lane < 16) ? red[lane] : 0.f;
    v = wave_sum_f(v);
    if (lane == 0) bcast = v;
  }
  __syncthreads();
  const float S = bcast;
  float acc = 0.f;
  for (int n = wv; n < 8192; n += 16) {
    acc += sl[n] * bf2f(Q[(long)(b * 8192 + n) * 512 + h * 64 + lane]);
  }
  __syncthreads();
  sl[wv * 64 + lane] = acc;
  __syncthreads();
  if (tid < 64) {
    float t = 0.f;
    #pragma unroll
    for (int w2 = 0; w2 < 16; ++w2) t += sl[w2 * 64 + tid];
    gq[bh * 64 + tid] = t / S;
  }
}

// ---------------- stage 2 pooling: softmax over N of (K*gq)·k_beta, weighted V sum
__global__ __launch_bounds__(1024) void pool_stage2(
    const ushort* __restrict__ Km, const ushort* __restrict__ Vm,
    const float* __restrict__ kb, const float* __restrict__ gq,
    const float* __restrict__ mask, float* __restrict__ gv)
{
  __shared__ float sl[8192];
  __shared__ float red[16];
  __shared__ float wvec[64];
  __shared__ float bcast;
  const int bh = blockIdx.x;
  const int b = bh >> 3, h = bh & 7;
  const int tid = threadIdx.x, lane = tid & 63, wv = tid >> 6;
  if (tid < 64) wvec[tid] = gq[bh * 64 + tid] * kb[h * 64 + tid];
  __syncthreads();
  const float scale = 0.125f;
  float lmax = -INFINITY;
  for (int n = tid; n < 8192; n += 1024) {
    const ushort* kp = Km + ((long)(b * 8192 + n) * 512 + h * 64);
    float dot = 0.f;
    #pragma unroll
    for (int c = 0; c < 8; ++c) {
      s8v v = *(const s8v*)(kp + c * 8);
      #pragma unroll
      for (int j = 0; j < 8; ++j) dot += bf2f((ushort)v[j]) * wvec[c * 8 + j];
    }
    float lg = dot * scale;
    if (mask[b * 8192 + n] == 0.f) lg = -INFINITY;
    sl[n] = lg;
    lmax = fmaxf(lmax, lg);
  }
  lmax = wave_max_f(lmax);
  if (lane == 0) red[wv] = lmax;
  __syncthreads();
  if (tid < 64) {
    float v = (lane < 16) ? red[lane] : -INFINITY;
    v = wave_max_f(v);
    if (lane == 0) bcast = v;
  }
  __syncthreads();
  const float gmax = bcast;
  float lsum = 0.f;
  for (int n = tid; n < 8192; n += 1024) {
    float e = __expf(sl[n] - gmax);
    sl[n] = e;
    lsum += e;
  }
  lsum = wave_sum_f(lsum);
  __syncthreads();
  if (lane == 0) red[wv] = lsum;
  __syncthreads();
  if (tid < 64) {
    float v = (lane < 16) ? red[lane] : 0.f;
    v = wave_sum_f(v);
    if (lane == 0) bcast = v;
  }
  __syncthreads();
  const float S = bcast;
  float acc = 0.f;
  for (int n = wv; n < 8192; n += 16) {
    acc += sl[n] * bf2f(Vm[(long)(b * 8192 + n) * 512 + h * 64 + lane]);
  }
  __syncthreads();
  sl[wv * 64 + lane] = acc;
  __syncthreads();
  if (tid < 64) {
    float t = 0.f;
    #pragma unroll
    for (int w2 = 0; w2 < 16; ++w2) t += sl[w2 * 64 + tid];
    gv[bh * 64 + tid] = t / S;
  }
}

// ---------------- attn_in = bf16(Q + global_v broadcast) ----------------
__global__ __launch_bounds__(256) void addv_kernel(
    const ushort* __restrict__ Q, const float* __restrict__ gv,
    ushort* __restrict__ out)
{
  const long i = ((long)blockIdx.x * 256 + threadIdx.x) * 8;
  const long row = i >> 9;
  const int c = (int)(i & 511);
  const int b = (int)(row >> 13);
  const int h = c >> 6, d0 = c & 63;
  const float* g = gv + ((long)((b << 3) + h)) * 64 + d0;
  s8v q = *(const s8v*)(Q + i);
  s8v o;
  #pragma unroll
  for (int j = 0; j < 8; ++j) o[j] = (short)f2bf(bf2f((ushort)q[j]) + g[j]);
  *(s8v*)(out + i) = o;
}

// ---------------- host ----------------
extern "C" void kernel_launch(void* const* d_in, const int* in_sizes, int n_in,
                              void* d_out, int out_size, void* d_ws, size_t ws_size,
                              hipStream_t stream) {
  const float* x    = (const float*)d_in[0];
  const float* mask = (const float*)d_in[1];
  const float* Wq   = (const float*)d_in[2];
  const float* bq   = (const float*)d_in[3];
  const float* Wk   = (const float*)d_in[4];
  const float* bk   = (const float*)d_in[5];
  const float* Wv   = (const float*)d_in[6];
  const float* bv   = (const float*)d_in[7];
  const float* qa   = (const float*)d_in[8];
  const float* kb   = (const float*)d_in[9];
  const float* Wo   = (const float*)d_in[10];
  const float* bo   = (const float*)d_in[11];
  const float* g0   = (const float*)d_in[12];
  const float* be0  = (const float*)d_in[13];
  const float* g1   = (const float*)d_in[14];
  const float* be1  = (const float*)d_in[15];
  const float* W1   = (const float*)d_in[16];
  const float* b1   = (const float*)d_in[17];
  const float* W2   = (const float*)d_in[18];
  const float* b2   = (const float*)d_in[19];
  float* out = (float*)d_out;

  const int M = 65536;          // B*N
  char* ws = (char*)d_ws;
  const size_t MB = 1024 * 1024;
  ushort* XN = (ushort*)(ws);             // 64MB: xn / attn_in / xn1
  float*  X1 = (float*)(ws + 64 * MB);    // 128MB: x after attention block
  ushort* Qb = (ushort*)(ws + 192 * MB);  // 64MB
  ushort* Kb = (ushort*)(ws + 256 * MB);  // 64MB
  ushort* Vb = (ushort*)(ws + 320 * MB);  // 64MB
  ushort* H1 = (ushort*)(ws + 192 * MB);  // 256MB, overlays Q/K/V (dead by then)
  float*  GQ = (float*)(ws + 448 * MB);
  float*  GV = (float*)(ws + 448 * MB + 16 * 1024);
  ushort* WQB = (ushort*)(ws + 448 * MB + 64 * 1024);
  ushort* WKB = WQB + 262144;
  ushort* WVB = WKB + 262144;
  ushort* WOB = WVB + 262144;
  ushort* W1B = WOB + 262144;
  ushort* W2B = W1B + 1048576;

  // weight conversions
  cvt_f32_bf16<<<256, 256, 0, stream>>>(Wq, WQB, 262144);
  cvt_f32_bf16<<<256, 256, 0, stream>>>(Wk, WKB, 262144);
  cvt_f32_bf16<<<256, 256, 0, stream>>>(Wv, WVB, 262144);
  cvt_f32_bf16<<<256, 256, 0, stream>>>(Wo, WOB, 262144);
  cvt_f32_bf16<<<1024, 256, 0, stream>>>(W1, W1B, 1048576);
  cvt_f32_bf16<<<1024, 256, 0, stream>>>(W2, W2B, 1048576);

  // LN0 (+mask)
  ln_rows<<<M / 4, 256, 0, stream>>>(x, g0, be0, mask, XN);

  // QKV GEMMs
  dim3 g512(512 / BNT, M / BMT);
  gemm_bt<0><<<g512, 256, 0, stream>>>(XN, WQB, bq, nullptr, nullptr, Qb, M, 512, 512);
  gemm_bt<0><<<g512, 256, 0, stream>>>(XN, WKB, bk, nullptr, nullptr, Kb, M, 512, 512);
  gemm_bt<0><<<g512, 256, 0, stream>>>(XN, WVB, bv, nullptr, nullptr, Vb, M, 512, 512);

  // pooling
  pool_stage1<<<64, 1024, 0, stream>>>(Qb, qa, mask, GQ);
  pool_stage2<<<64, 1024, 0, stream>>>(Kb, Vb, kb, GQ, mask, GV);

  // attn_in = Q + global_v  (overwrites XN, which is dead)
  addv_kernel<<<(int)((long)M * 512 / 8 / 256), 256, 0, stream>>>(Qb, GV, XN);

  // Wo GEMM + residual -> X1 (f32)
  gemm_bt<1><<<g512, 256, 0, stream>>>(XN, WOB, bo, x, nullptr, X1, M, 512, 512);

  // LN1 -> XN (bf16)
  ln_rows<<<M / 4, 256, 0, stream>>>(X1, g1, be1, nullptr, XN);

  // MLP
  dim3 g2048(2048 / BNT, M / BMT);
  gemm_bt<2><<<g2048, 256, 0, stream>>>(XN, W1B, b1, nullptr, nullptr, H1, M, 2048, 512);
  gemm_bt<3><<<g512, 256, 0, stream>>>(H1, W2B, b2, X1, mask, out, M, 512, 2048);
}